// Round 3
// baseline (693.090 us; speedup 1.0000x reference)
//
#include <hip/hip_runtime.h>

#define LSTR 264  // 256 + 8 shorts pad: 528B rows keep 16B alignment for ds_read_b128
#define TILES 4

typedef short short4v __attribute__((ext_vector_type(4)));
typedef short short8v __attribute__((ext_vector_type(8)));
typedef float f32x4 __attribute__((ext_vector_type(4)));

#define MFMA(a, b, c) __builtin_amdgcn_mfma_f32_16x16x32_bf16((a), (b), (c), 0, 0, 0)

__device__ __forceinline__ short f2bf(float f) {
  unsigned u = __float_as_uint(f);
  unsigned r = u + 0x7fffu + ((u >> 16) & 1u);  // round-to-nearest-even
  return (short)(r >> 16);
}

__device__ __forceinline__ short4v f2bf4(float4 v) {
  short4v s;
  s.x = f2bf(v.x); s.y = f2bf(v.y); s.z = f2bf(v.z); s.w = f2bf(v.w);
  return s;
}

// Packed-fragment index for B weights: row n = h*64 + nt*16 + col, k = ks*32 + quad*8 + j
// -> packed[h*16384 + (ks*4+nt)*512 + (quad*16+col)*8 + j]
// A wave's B-fragment load is ONE contiguous 1KB global_load_dwordx4.

// Merged prep: blocks 0..255 compute wvo = Wo@Wv (packed bf16) + bvo = Wo@bv+bo;
// blocks 256..287 pack Wq/Wk/Wv/Wo into fragment order.
__global__ __launch_bounds__(256) void prep_kernel(
    const float* __restrict__ Wq, const float* __restrict__ Wk,
    const float* __restrict__ Wv, const float* __restrict__ Wo,
    const float* __restrict__ bv, const float* __restrict__ bo,
    short* __restrict__ pq, short* __restrict__ pk,
    short* __restrict__ pv, short* __restrict__ po,
    short* __restrict__ pvo, float* __restrict__ bvo) {
  __shared__ float srow[256];
  __shared__ float red[256];
  if (blockIdx.x < 256) {
    const int n = blockIdx.x, k = threadIdx.x;
    const float wov = Wo[n * 256 + k];
    srow[k] = wov;
    red[k] = wov * bv[k];
    __syncthreads();
    float acc = 0.f;
#pragma unroll 16
    for (int j = 0; j < 256; ++j) acc += srow[j] * Wv[j * 256 + k];
    const int h = n >> 6, nt = (n >> 4) & 3, col = n & 15;
    const int ks = k >> 5, quad = (k >> 3) & 3, j8 = k & 7;
    pvo[h * 16384 + (ks * 4 + nt) * 512 + (quad * 16 + col) * 8 + j8] = f2bf(acc);
    for (int s = 128; s > 0; s >>= 1) {
      if (k < s) red[k] += red[k + s];
      __syncthreads();
    }
    if (k == 0) bvo[n] = red[0] + bo[n];
  } else {
    const int g = (blockIdx.x - 256) * 256 + threadIdx.x;  // 0..8191
    const int n = g >> 5;
    const int c8 = g & 31;
    const int h = n >> 6, nt = (n >> 4) & 3, col = n & 15;
    const int ks = c8 >> 2, quad = c8 & 3;
    const int src = n * 256 + c8 * 8;
    const int dst = h * 16384 + (ks * 4 + nt) * 512 + (quad * 16 + col) * 8;
    const float4* q4 = (const float4*)(Wq + src);
    const float4* k4 = (const float4*)(Wk + src);
    const float4* v4 = (const float4*)(Wv + src);
    const float4* o4 = (const float4*)(Wo + src);
    float4 qa = q4[0], qb = q4[1], ka = k4[0], kb = k4[1];
    float4 va = v4[0], vb = v4[1], oa = o4[0], ob = o4[1];
    *(short4v*)(pq + dst) = f2bf4(qa); *(short4v*)(pq + dst + 4) = f2bf4(qb);
    *(short4v*)(pk + dst) = f2bf4(ka); *(short4v*)(pk + dst + 4) = f2bf4(kb);
    *(short4v*)(pv + dst) = f2bf4(va); *(short4v*)(pv + dst + 4) = f2bf4(vb);
    *(short4v*)(po + dst) = f2bf4(oa); *(short4v*)(po + dst + 4) = f2bf4(ob);
  }
}

// Merged Q+K pass: two A tiles (p, d), two independent B streams (pq, pk),
// two accumulator sets; B prefetch depth-3 per stream.
__device__ __forceinline__ void gemm_qk(const short* Ap, const short* Ad,
                                        const short* __restrict__ wq,
                                        const short* __restrict__ wk,
                                        int col, int quad,
                                        f32x4 accQ[2][4], f32x4 accK[2][4]) {
  const short* p0 = Ap + col * LSTR + quad * 8;
  const short* p1 = p0 + 16 * LSTR;
  const short* d0 = Ad + col * LSTR + quad * 8;
  const short* d1 = d0 + 16 * LSTR;
  short8v ap0 = *(const short8v*)p0;
  short8v ap1 = *(const short8v*)p1;
  short8v ad0 = *(const short8v*)d0;
  short8v ad1 = *(const short8v*)d1;
  short8v qb0 = *(const short8v*)(wq);
  short8v qb1 = *(const short8v*)(wq + 512);
  short8v qb2 = *(const short8v*)(wq + 1024);
  short8v kb0 = *(const short8v*)(wk);
  short8v kb1 = *(const short8v*)(wk + 512);
  short8v kb2 = *(const short8v*)(wk + 1024);
#pragma unroll
  for (int ks = 0; ks < 8; ++ks) {
    const int kn = (ks + 1) & 7;  // wrap avoids OOB; tail reloads are free
    short8v ap0n = *(const short8v*)(p0 + kn * 32);
    short8v ap1n = *(const short8v*)(p1 + kn * 32);
    short8v ad0n = *(const short8v*)(d0 + kn * 32);
    short8v ad1n = *(const short8v*)(d1 + kn * 32);
#pragma unroll
    for (int nt = 0; nt < 4; ++nt) {
      const int f = ks * 4 + nt;
      short8v qbn = *(const short8v*)(wq + ((f + 3) & 31) * 512);
      short8v kbn = *(const short8v*)(wk + ((f + 3) & 31) * 512);
      accQ[0][nt] = MFMA(ap0, qb0, accQ[0][nt]);
      accQ[1][nt] = MFMA(ap1, qb0, accQ[1][nt]);
      accK[0][nt] = MFMA(ad0, kb0, accK[0][nt]);
      accK[1][nt] = MFMA(ad1, kb0, accK[1][nt]);
      qb0 = qb1; qb1 = qb2; qb2 = qbn;
      kb0 = kb1; kb1 = kb2; kb2 = kbn;
    }
    ap0 = ap0n; ap1 = ap1n; ad0 = ad0n; ad1 = ad1n;
  }
}

// Single-A pass (V): B prefetch depth-4.
__device__ __forceinline__ void gemm_v(const short* A, const short* __restrict__ wb,
                                       int col, int quad, f32x4 acc[2][4]) {
  const short* a0p = A + col * LSTR + quad * 8;
  const short* a1p = a0p + 16 * LSTR;
  short8v a0c = *(const short8v*)a0p;
  short8v a1c = *(const short8v*)a1p;
  short8v b0 = *(const short8v*)(wb);
  short8v b1 = *(const short8v*)(wb + 512);
  short8v b2 = *(const short8v*)(wb + 1024);
  short8v b3 = *(const short8v*)(wb + 1536);
#pragma unroll
  for (int ks = 0; ks < 8; ++ks) {
    const int kn = (ks + 1) & 7;
    short8v a0n = *(const short8v*)(a0p + kn * 32);
    short8v a1n = *(const short8v*)(a1p + kn * 32);
#pragma unroll
    for (int nt = 0; nt < 4; ++nt) {
      const int f = ks * 4 + nt;
      short8v bn = *(const short8v*)(wb + ((f + 4) & 31) * 512);
      acc[0][nt] = MFMA(a0c, b0, acc[0][nt]);
      acc[1][nt] = MFMA(a1c, b0, acc[1][nt]);
      b0 = b1; b1 = b2; b2 = b3; b3 = bn;
    }
    a0c = a0n; a1c = a1n;
  }
}

// Merged O pass: two A tiles (c1, gdV), two B streams (pvo, po), two acc sets.
__device__ __forceinline__ void gemm_o(const short* Ac, const short* Ag,
                                       const short* __restrict__ wvo,
                                       const short* __restrict__ wo,
                                       int col, int quad,
                                       f32x4 accA[2][4], f32x4 accB[2][4]) {
  const short* c0p = Ac + col * LSTR + quad * 8;
  const short* c1p = c0p + 16 * LSTR;
  const short* g0p = Ag + col * LSTR + quad * 8;
  const short* g1p = g0p + 16 * LSTR;
  short8v ac0 = *(const short8v*)c0p;
  short8v ac1 = *(const short8v*)c1p;
  short8v ag0 = *(const short8v*)g0p;
  short8v ag1 = *(const short8v*)g1p;
  short8v vb0 = *(const short8v*)(wvo);
  short8v vb1 = *(const short8v*)(wvo + 512);
  short8v vb2 = *(const short8v*)(wvo + 1024);
  short8v ob0 = *(const short8v*)(wo);
  short8v ob1 = *(const short8v*)(wo + 512);
  short8v ob2 = *(const short8v*)(wo + 1024);
#pragma unroll
  for (int ks = 0; ks < 8; ++ks) {
    const int kn = (ks + 1) & 7;
    short8v ac0n = *(const short8v*)(c0p + kn * 32);
    short8v ac1n = *(const short8v*)(c1p + kn * 32);
    short8v ag0n = *(const short8v*)(g0p + kn * 32);
    short8v ag1n = *(const short8v*)(g1p + kn * 32);
#pragma unroll
    for (int nt = 0; nt < 4; ++nt) {
      const int f = ks * 4 + nt;
      short8v vbn = *(const short8v*)(wvo + ((f + 3) & 31) * 512);
      short8v obn = *(const short8v*)(wo + ((f + 3) & 31) * 512);
      accA[0][nt] = MFMA(ac0, vb0, accA[0][nt]);
      accA[1][nt] = MFMA(ac1, vb0, accA[1][nt]);
      accB[0][nt] = MFMA(ag0, ob0, accB[0][nt]);
      accB[1][nt] = MFMA(ag1, ob0, accB[1][nt]);
      vb0 = vb1; vb1 = vb2; vb2 = vbn;
      ob0 = ob1; ob1 = ob2; ob2 = obn;
    }
    ac0 = ac0n; ac1 = ac1n; ag0 = ag0n; ag1 = ag1n;
  }
}

// Persistent: 512 blocks x TILES row-tiles. Next tile's 24 global loads are
// issued right after the current tile's LDS staging writes, so their HBM
// latency hides under ~2 full GEMM passes (T14 issue-early/consume-late).
__global__ __launch_bounds__(256, 2) void fused_kernel(
    const float* __restrict__ pred, const float* __restrict__ cemb,
    const short* __restrict__ pq, const short* __restrict__ pk,
    const short* __restrict__ pv, const short* __restrict__ po,
    const short* __restrict__ pvo, const float* __restrict__ bq,
    const float* __restrict__ bvo, float* __restrict__ out) {
  __shared__ __align__(16) short bufP[32 * LSTR];   // p tile, later gdV tile
  __shared__ __align__(16) short bufD[32 * LSTR];   // c0-c1 tile
  __shared__ __align__(16) short bufC1[32 * LSTR];  // c1 tile
  const int tid = threadIdx.x;
  const int lane = tid & 63;
  const int w = tid >> 6;  // wave = head
  const int col = lane & 15;
  const int quad = lane >> 4;
  const int nbase = w * 64;
  const int woff = w * 16384 + lane * 8;
  const int r = tid >> 3;
  const int c8 = tid & 7;

  float bqv[4], bov[4];
#pragma unroll
  for (int nt = 0; nt < 4; ++nt) bqv[nt] = bq[nbase + nt * 16 + col];
#pragma unroll
  for (int nt = 0; nt < 4; ++nt) bov[nt] = bvo[nbase + nt * 16 + col];

  // Prologue: load tile 0 into held registers (24 x dwordx4 per thread).
  float4 pv_[8], av[8], bw[8];
  {
    const size_t t0 = (size_t)blockIdx.x * TILES * 32;
    const float4* prow = (const float4*)(pred + (t0 + r) * 256);
    const float4* crow = (const float4*)(cemb + (t0 + r) * 512);
#pragma unroll
    for (int i = 0; i < 8; ++i) pv_[i] = prow[c8 + 8 * i];
#pragma unroll
    for (int i = 0; i < 8; ++i) av[i] = crow[c8 + 8 * i];
#pragma unroll
    for (int i = 0; i < 8; ++i) bw[i] = crow[64 + c8 + 8 * i];
  }

  for (int it = 0; it < TILES; ++it) {
    const size_t t0 = ((size_t)blockIdx.x * TILES + it) * 32;

    // Stage: convert held regs -> bf16 LDS tiles (consumes pv_/av/bw) ...
    {
      short* pd = bufP + r * LSTR;
      short* dd = bufD + r * LSTR;
      short* cd = bufC1 + r * LSTR;
#pragma unroll
      for (int i = 0; i < 8; ++i) {
        const int j = c8 + 8 * i;
        *(short4v*)(pd + 4 * j) = f2bf4(pv_[i]);
        float4 d4 = make_float4(av[i].x - bw[i].x, av[i].y - bw[i].y,
                                av[i].z - bw[i].z, av[i].w - bw[i].w);
        *(short4v*)(dd + 4 * j) = f2bf4(d4);
        *(short4v*)(cd + 4 * j) = f2bf4(bw[i]);
      }
    }
    // ... then immediately issue next tile's loads into the same registers
    // (WAR-safe: all consuming VALU ops issued before the loads). They stay
    // in flight across both GEMM passes below.
    if (it + 1 < TILES) {
      const float4* prow = (const float4*)(pred + (t0 + 32 + r) * 256);
      const float4* crow = (const float4*)(cemb + (t0 + 32 + r) * 512);
#pragma unroll
      for (int i = 0; i < 8; ++i) pv_[i] = prow[c8 + 8 * i];
#pragma unroll
      for (int i = 0; i < 8; ++i) av[i] = crow[c8 + 8 * i];
#pragma unroll
      for (int i = 0; i < 8; ++i) bw[i] = crow[64 + c8 + 8 * i];
    }
    __syncthreads();

    // Pass 1: Q and dK GEMMs, merged (dual VMEM streams).
    f32x4 accQ[2][4] = {};
    f32x4 accK[2][4] = {};
    gemm_qk(bufP, bufD, pq + woff, pk + woff, col, quad, accQ, accK);

    // z[m][head] = (Q+bq) . dK over this head's 64 cols; reduce across the
    // 16 lanes of each quad-row; g = sigmoid(z/sqrt(D))
    float g[2][4];
#pragma unroll
    for (int ms = 0; ms < 2; ++ms) {
#pragma unroll
      for (int rr = 0; rr < 4; ++rr) {
        float zz = 0.f;
#pragma unroll
        for (int nt = 0; nt < 4; ++nt)
          zz += (accQ[ms][nt][rr] + bqv[nt]) * accK[ms][nt][rr];
        zz += __shfl_xor(zz, 1);
        zz += __shfl_xor(zz, 2);
        zz += __shfl_xor(zz, 4);
        zz += __shfl_xor(zz, 8);
        g[ms][rr] = 1.f / (1.f + __expf(-0.125f * zz));
      }
    }

    // Pass 2: dV GEMM.
    f32x4 accV[2][4] = {};
    gemm_v(bufD, pv + woff, col, quad, accV);

    __syncthreads();  // all waves done reading bufP (Q gemm)
    // gdV -> bufP as bf16 A-tile (C/D layout: row = quad*4+reg, col = nt*16+col)
#pragma unroll
    for (int ms = 0; ms < 2; ++ms)
#pragma unroll
      for (int nt = 0; nt < 4; ++nt)
#pragma unroll
        for (int rr = 0; rr < 4; ++rr)
          bufP[(ms * 16 + quad * 4 + rr) * LSTR + nbase + nt * 16 + col] =
              f2bf(g[ms][rr] * accV[ms][nt][rr]);
    __syncthreads();

    // Pass 3: out = c1 @ Wvo^T + gdV @ Wo^T + bvo, merged (dual A, dual B).
    f32x4 accO1[2][4] = {};
    f32x4 accO2[2][4] = {};
    gemm_o(bufC1, bufP, pvo + woff, po + woff, col, quad, accO1, accO2);

#pragma unroll
    for (int ms = 0; ms < 2; ++ms)
#pragma unroll
      for (int nt = 0; nt < 4; ++nt)
#pragma unroll
        for (int rr = 0; rr < 4; ++rr)
          out[(t0 + ms * 16 + quad * 4 + rr) * 256 + nbase + nt * 16 + col] =
              accO1[ms][nt][rr] + accO2[ms][nt][rr] + bov[nt];

    __syncthreads();  // all waves done with bufP/bufC1 before next stage
  }
}

extern "C" void kernel_launch(void* const* d_in, const int* in_sizes, int n_in,
                              void* d_out, int out_size, void* d_ws, size_t ws_size,
                              hipStream_t stream) {
  const float* pred = (const float*)d_in[0];
  const float* cemb = (const float*)d_in[1];
  const float* Wq = (const float*)d_in[2];
  const float* bq = (const float*)d_in[3];
  const float* Wk = (const float*)d_in[4];
  const float* Wv = (const float*)d_in[6];
  const float* bv = (const float*)d_in[7];
  const float* Wo = (const float*)d_in[8];
  const float* bo = (const float*)d_in[9];
  float* out = (float*)d_out;

  short* pq = (short*)d_ws;
  short* pk = pq + 65536;
  short* pv = pk + 65536;
  short* po = pv + 65536;
  short* pvo = po + 65536;
  float* bvo = (float*)(pvo + 65536);  // total ws use: 656,384 bytes

  prep_kernel<<<288, 256, 0, stream>>>(Wq, Wk, Wv, Wo, bv, bo, pq, pk, pv, po, pvo, bvo);
  fused_kernel<<<512, 256, 0, stream>>>(pred, cemb, pq, pk, pv, po, pvo, bq, bvo, out);
}

// Round 5
// 562.424 us; speedup vs baseline: 1.2323x; 1.2323x over previous
//
#include <hip/hip_runtime.h>

typedef short short4v __attribute__((ext_vector_type(4)));
typedef short short8v __attribute__((ext_vector_type(8)));
typedef float f32x4 __attribute__((ext_vector_type(4)));

#define MFMA(a, b, c) __builtin_amdgcn_mfma_f32_16x16x32_bf16((a), (b), (c), 0, 0, 0)

__device__ __forceinline__ short f2bf(float f) {
  unsigned u = __float_as_uint(f);
  unsigned r = u + 0x7fffu + ((u >> 16) & 1u);  // round-to-nearest-even
  return (short)(r >> 16);
}

__device__ __forceinline__ short4v f2bf4(float4 v) {
  short4v s;
  s.x = f2bf(v.x); s.y = f2bf(v.y); s.z = f2bf(v.z); s.w = f2bf(v.w);
  return s;
}

__device__ __forceinline__ short8v pack8(float4 a, float4 b) {
  short8v s;
  s[0] = f2bf(a.x); s[1] = f2bf(a.y); s[2] = f2bf(a.z); s[3] = f2bf(a.w);
  s[4] = f2bf(b.x); s[5] = f2bf(b.y); s[6] = f2bf(b.z); s[7] = f2bf(b.w);
  return s;
}

// Direct HBM->LDS, 16B per lane; LDS dest = wave-uniform base + lane*16.
__device__ __forceinline__ void gload_lds16(const void* g, void* l) {
  __builtin_amdgcn_global_load_lds(
      (const __attribute__((address_space(1))) unsigned int*)g,
      (__attribute__((address_space(3))) unsigned int*)l, 16, 0, 0);
}

// ---------------------------------------------------------------------------
// Tile image format (bf16, shorts): [32 rows][256 k], stored as 16B chunks
// with chunk index XOR-swizzled within each row: chunk c of row r lives at
//   r*256 + ((c ^ (r&7)) * 8)
// A-fragment reads (row = ms*16+col, chunk = ks*4+quad) then land on 8
// distinct bank-quads per 16-lane group -> minimum aliasing for b128.
// One tile's staging = d-image (16KB) then c1-image (16KB) = 32KB, placed
// AT the tile's own 32KB out-region (read strictly before out is written).
// ---------------------------------------------------------------------------

__device__ __forceinline__ int aoff(int ks, int quad, int x7) {
  return (((ks * 4 + quad) ^ x7) << 3);
}

// Packed-fragment index for B weights: row n = h*64 + nt*16 + col, k = ks*32 + quad*8 + j
// -> packed[h*16384 + (ks*4+nt)*512 + (quad*16+col)*8 + j]
// A wave's B-fragment load is ONE contiguous 1KB global_load_dwordx4.

// Merged prep: blocks 0..255 compute wvo = Wo@Wv (packed bf16) + bvo = Wo@bv+bo;
// blocks 256..287 pack Wq/Wk/Wv/Wo into fragment order.
__global__ __launch_bounds__(256) void prep_kernel(
    const float* __restrict__ Wq, const float* __restrict__ Wk,
    const float* __restrict__ Wv, const float* __restrict__ Wo,
    const float* __restrict__ bv, const float* __restrict__ bo,
    short* __restrict__ pq, short* __restrict__ pk,
    short* __restrict__ pv, short* __restrict__ po,
    short* __restrict__ pvo, float* __restrict__ bvo) {
  __shared__ float srow[256];
  __shared__ float red[256];
  if (blockIdx.x < 256) {
    const int n = blockIdx.x, k = threadIdx.x;
    const float wov = Wo[n * 256 + k];
    srow[k] = wov;
    red[k] = wov * bv[k];
    __syncthreads();
    float acc = 0.f;
#pragma unroll 16
    for (int j = 0; j < 256; ++j) acc += srow[j] * Wv[j * 256 + k];
    const int h = n >> 6, nt = (n >> 4) & 3, col = n & 15;
    const int ks = k >> 5, quad = (k >> 3) & 3, j8 = k & 7;
    pvo[h * 16384 + (ks * 4 + nt) * 512 + (quad * 16 + col) * 8 + j8] = f2bf(acc);
    for (int s = 128; s > 0; s >>= 1) {
      if (k < s) red[k] += red[k + s];
      __syncthreads();
    }
    if (k == 0) bvo[n] = red[0] + bo[n];
  } else {
    const int g = (blockIdx.x - 256) * 256 + threadIdx.x;  // 0..8191
    const int n = g >> 5;
    const int c8 = g & 31;
    const int h = n >> 6, nt = (n >> 4) & 3, col = n & 15;
    const int ks = c8 >> 2, quad = c8 & 3;
    const int src = n * 256 + c8 * 8;
    const int dst = h * 16384 + (ks * 4 + nt) * 512 + (quad * 16 + col) * 8;
    const float4* q4 = (const float4*)(Wq + src);
    const float4* k4 = (const float4*)(Wk + src);
    const float4* v4 = (const float4*)(Wv + src);
    const float4* o4 = (const float4*)(Wo + src);
    float4 qa = q4[0], qb = q4[1], ka = k4[0], kb = k4[1];
    float4 va = v4[0], vb = v4[1], oa = o4[0], ob = o4[1];
    *(short4v*)(pq + dst) = f2bf4(qa); *(short4v*)(pq + dst + 4) = f2bf4(qb);
    *(short4v*)(pk + dst) = f2bf4(ka); *(short4v*)(pk + dst + 4) = f2bf4(kb);
    *(short4v*)(pv + dst) = f2bf4(va); *(short4v*)(pv + dst + 4) = f2bf4(vb);
    *(short4v*)(po + dst) = f2bf4(oa); *(short4v*)(po + dst + 4) = f2bf4(ob);
  }
}

// restage: cemb fp32 -> per-tile staged images (d = c0-c1, c1) in bf16,
// chunk-XOR layout, written into the out buffer (tile t -> out bytes
// [t*32768, t*32768+32768)). Pure streaming, fully coalesced reads; writes
// are dense within 512B rows (chunk-permuted).
__global__ __launch_bounds__(256) void restage_kernel(
    const float* __restrict__ cemb, short* __restrict__ staged) {
  const int tile = blockIdx.x;
  const int c = threadIdx.x & 31;   // 16B chunk within row (8 floats)
  const int r0 = threadIdx.x >> 5;  // 0..7
  short* timg = staged + (size_t)tile * 16384;
  const float* tsrc = cemb + (size_t)tile * 32 * 512;
#pragma unroll
  for (int rr = 0; rr < 4; ++rr) {
    const int r = r0 + rr * 8;
    const float* c0 = tsrc + r * 512 + c * 8;
    const float* c1 = c0 + 256;
    float4 a0 = *(const float4*)(c0);
    float4 a1 = *(const float4*)(c0 + 4);
    float4 b0 = *(const float4*)(c1);
    float4 b1 = *(const float4*)(c1 + 4);
    float4 d0 = make_float4(a0.x - b0.x, a0.y - b0.y, a0.z - b0.z, a0.w - b0.w);
    float4 d1 = make_float4(a1.x - b1.x, a1.y - b1.y, a1.z - b1.z, a1.w - b1.w);
    const int cx = (c ^ (r & 7)) * 8;
    *(short8v*)(timg + r * 256 + cx) = pack8(d0, d1);
    *(short8v*)(timg + 8192 + r * 256 + cx) = pack8(b0, b1);
  }
}

// Merged Q+K pass: A tiles from XOR-swizzled images; B streams depth-3.
__device__ __forceinline__ void gemm_qk(const short* Ap, const short* Ad,
                                        const short* __restrict__ wq,
                                        const short* __restrict__ wk,
                                        int col, int quad,
                                        f32x4 accQ[2][4], f32x4 accK[2][4]) {
  const int x7 = col & 7;
  const int r0 = col * 256, r1 = r0 + 4096;
  short8v ap0 = *(const short8v*)(Ap + r0 + aoff(0, quad, x7));
  short8v ap1 = *(const short8v*)(Ap + r1 + aoff(0, quad, x7));
  short8v ad0 = *(const short8v*)(Ad + r0 + aoff(0, quad, x7));
  short8v ad1 = *(const short8v*)(Ad + r1 + aoff(0, quad, x7));
  short8v qb0 = *(const short8v*)(wq);
  short8v qb1 = *(const short8v*)(wq + 512);
  short8v qb2 = *(const short8v*)(wq + 1024);
  short8v kb0 = *(const short8v*)(wk);
  short8v kb1 = *(const short8v*)(wk + 512);
  short8v kb2 = *(const short8v*)(wk + 1024);
#pragma unroll
  for (int ks = 0; ks < 8; ++ks) {
    const int kn = (ks + 1) & 7;  // wrap avoids OOB; tail reloads are free
    short8v ap0n = *(const short8v*)(Ap + r0 + aoff(kn, quad, x7));
    short8v ap1n = *(const short8v*)(Ap + r1 + aoff(kn, quad, x7));
    short8v ad0n = *(const short8v*)(Ad + r0 + aoff(kn, quad, x7));
    short8v ad1n = *(const short8v*)(Ad + r1 + aoff(kn, quad, x7));
#pragma unroll
    for (int nt = 0; nt < 4; ++nt) {
      const int f = ks * 4 + nt;
      short8v qbn = *(const short8v*)(wq + ((f + 3) & 31) * 512);
      short8v kbn = *(const short8v*)(wk + ((f + 3) & 31) * 512);
      accQ[0][nt] = MFMA(ap0, qb0, accQ[0][nt]);
      accQ[1][nt] = MFMA(ap1, qb0, accQ[1][nt]);
      accK[0][nt] = MFMA(ad0, kb0, accK[0][nt]);
      accK[1][nt] = MFMA(ad1, kb0, accK[1][nt]);
      qb0 = qb1; qb1 = qb2; qb2 = qbn;
      kb0 = kb1; kb1 = kb2; kb2 = kbn;
    }
    ap0 = ap0n; ap1 = ap1n; ad0 = ad0n; ad1 = ad1n;
  }
}

// Single-A pass (V): B prefetch depth-4.
__device__ __forceinline__ void gemm_v(const short* Ad, const short* __restrict__ wb,
                                       int col, int quad, f32x4 acc[2][4]) {
  const int x7 = col & 7;
  const int r0 = col * 256, r1 = r0 + 4096;
  short8v a0 = *(const short8v*)(Ad + r0 + aoff(0, quad, x7));
  short8v a1 = *(const short8v*)(Ad + r1 + aoff(0, quad, x7));
  short8v b0 = *(const short8v*)(wb);
  short8v b1 = *(const short8v*)(wb + 512);
  short8v b2 = *(const short8v*)(wb + 1024);
  short8v b3 = *(const short8v*)(wb + 1536);
#pragma unroll
  for (int ks = 0; ks < 8; ++ks) {
    const int kn = (ks + 1) & 7;
    short8v a0n = *(const short8v*)(Ad + r0 + aoff(kn, quad, x7));
    short8v a1n = *(const short8v*)(Ad + r1 + aoff(kn, quad, x7));
#pragma unroll
    for (int nt = 0; nt < 4; ++nt) {
      const int f = ks * 4 + nt;
      short8v bn = *(const short8v*)(wb + ((f + 4) & 31) * 512);
      acc[0][nt] = MFMA(a0, b0, acc[0][nt]);
      acc[1][nt] = MFMA(a1, b0, acc[1][nt]);
      b0 = b1; b1 = b2; b2 = b3; b3 = bn;
    }
    a0 = a0n; a1 = a1n;
  }
}

// Merged O pass: two A images (c1, gdV), two B streams, two acc sets.
__device__ __forceinline__ void gemm_o(const short* Ac, const short* Ag,
                                       const short* __restrict__ wvo,
                                       const short* __restrict__ wo,
                                       int col, int quad,
                                       f32x4 accA[2][4], f32x4 accB[2][4]) {
  const int x7 = col & 7;
  const int r0 = col * 256, r1 = r0 + 4096;
  short8v ac0 = *(const short8v*)(Ac + r0 + aoff(0, quad, x7));
  short8v ac1 = *(const short8v*)(Ac + r1 + aoff(0, quad, x7));
  short8v ag0 = *(const short8v*)(Ag + r0 + aoff(0, quad, x7));
  short8v ag1 = *(const short8v*)(Ag + r1 + aoff(0, quad, x7));
  short8v vb0 = *(const short8v*)(wvo);
  short8v vb1 = *(const short8v*)(wvo + 512);
  short8v vb2 = *(const short8v*)(wvo + 1024);
  short8v ob0 = *(const short8v*)(wo);
  short8v ob1 = *(const short8v*)(wo + 512);
  short8v ob2 = *(const short8v*)(wo + 1024);
#pragma unroll
  for (int ks = 0; ks < 8; ++ks) {
    const int kn = (ks + 1) & 7;
    short8v ac0n = *(const short8v*)(Ac + r0 + aoff(kn, quad, x7));
    short8v ac1n = *(const short8v*)(Ac + r1 + aoff(kn, quad, x7));
    short8v ag0n = *(const short8v*)(Ag + r0 + aoff(kn, quad, x7));
    short8v ag1n = *(const short8v*)(Ag + r1 + aoff(kn, quad, x7));
#pragma unroll
    for (int nt = 0; nt < 4; ++nt) {
      const int f = ks * 4 + nt;
      short8v vbn = *(const short8v*)(wvo + ((f + 3) & 31) * 512);
      short8v obn = *(const short8v*)(wo + ((f + 3) & 31) * 512);
      accA[0][nt] = MFMA(ac0, vb0, accA[0][nt]);
      accA[1][nt] = MFMA(ac1, vb0, accA[1][nt]);
      accB[0][nt] = MFMA(ag0, ob0, accB[0][nt]);
      accB[1][nt] = MFMA(ag1, ob0, accB[1][nt]);
      vb0 = vb1; vb1 = vb2; vb2 = vbn;
      ob0 = ob1; ob1 = ob2; ob2 = obn;
    }
    ac0 = ac0n; ac1 = ac1n; ag0 = ag0n; ag1 = ag1n;
  }
}

// Persistent: 512 blocks (exactly 2/CU) x 4 tiles. d/c1 arrive via
// global_load_lds (zero VGPR prefetch); d double-buffered one tile ahead,
// c1 issued at tile start and consumed at pass3; pred register-staged
// (32 VGPRs) issued after pass1, consumed at next tile start. Every
// prefetch has >=1 GEMM pass before the next barrier's implicit
// vmcnt-drain, so drains are free and HBM streams continuously.
__global__ __launch_bounds__(256, 2) void fused_kernel(
    const float* __restrict__ pred, const short* __restrict__ pq,
    const short* __restrict__ pk, const short* __restrict__ pv,
    const short* __restrict__ po, const short* __restrict__ pvo,
    const float* __restrict__ bq, const float* __restrict__ bvo,
    float* __restrict__ out) {
  __shared__ __align__(16) short bufD[2][8192];  // d image dbuf; [cur] reused for gdV
  __shared__ __align__(16) short bufC1[8192];    // c1 image
  __shared__ __align__(16) short bufP[8192];     // p image
  const int tid = threadIdx.x;
  const int lane = tid & 63;
  const int w = tid >> 6;  // wave = head
  const int col = lane & 15;
  const int quad = lane >> 4;
  const int nbase = w * 64;
  const int woff = w * 16384 + lane * 8;
  const int rA = tid >> 3;  // staging row 0..31
  const int c8 = tid & 7;   // staging half-chunk base
  const int tbase = blockIdx.x * 4;
  const short* stg = (const short*)out;  // staged images alias the out buffer

  float bqv[4], bov[4];
#pragma unroll
  for (int nt = 0; nt < 4; ++nt) bqv[nt] = bq[nbase + nt * 16 + col];
#pragma unroll
  for (int nt = 0; nt < 4; ++nt) bov[nt] = bvo[nbase + nt * 16 + col];

  // DMA one 16KB image (16 x 1KB wave-chunks; 4 per wave).
  auto dma_img = [&](const short* src, short* dst) {
#pragma unroll
    for (int i = 0; i < 4; ++i) {
      const int o = (w * 4 + i) * 512;
      gload_lds16(src + o + lane * 8, dst + o);
    }
  };

  // Prologue: DMA d_0, register-load p_0.
  float4 pv_[8];
  dma_img(stg + (size_t)tbase * 16384, bufD[0]);
  {
    const float4* prow = (const float4*)(pred + ((size_t)tbase * 32 + rA) * 256);
#pragma unroll
    for (int i = 0; i < 8; ++i) pv_[i] = prow[c8 + 8 * i];
  }

  for (int t = 0; t < 4; ++t) {
    short* dcur = bufD[t & 1];
    short* dnxt = bufD[(t + 1) & 1];
    const bool more = (t + 1) < 4;
    const size_t tg = (size_t)(tbase + t);

    // A: p regs -> bufP (XOR-chunk layout). Compiler auto-waits the p loads.
    {
      short* pd = bufP + rA * 256;
      const int rx = rA & 7;
#pragma unroll
      for (int i = 0; i < 8; ++i) {
        const int h = c8 + 8 * i;  // half-chunk 0..63
        *(short4v*)(pd + (((h >> 1) ^ rx) << 3) + (h & 1) * 4) = f2bf4(pv_[i]);
      }
    }
    // B: ensure d_t landed (t=0: prologue DMA; t>0: drained last tile).
    asm volatile("s_waitcnt vmcnt(0)" ::: "memory");
    __syncthreads();

    // D: prefetches — d_{t+1} (consumed next tile) and c1_t (consumed pass3).
    if (more) dma_img(stg + (size_t)(tbase + t + 1) * 16384, dnxt);
    dma_img(stg + tg * 16384 + 8192, bufC1);

    // Pass 1: Q & dK (dual B-stream).
    f32x4 accQ[2][4] = {};
    f32x4 accK[2][4] = {};
    gemm_qk(bufP, dcur, pq + woff, pk + woff, col, quad, accQ, accK);

    // g = sigmoid((Q+bq).dK / sqrt(D)), reduced over the head's 64 cols.
    float g[2][4];
#pragma unroll
    for (int ms = 0; ms < 2; ++ms) {
#pragma unroll
      for (int rr = 0; rr < 4; ++rr) {
        float zz = 0.f;
#pragma unroll
        for (int nt = 0; nt < 4; ++nt)
          zz += (accQ[ms][nt][rr] + bqv[nt]) * accK[ms][nt][rr];
        zz += __shfl_xor(zz, 1);
        zz += __shfl_xor(zz, 2);
        zz += __shfl_xor(zz, 4);
        zz += __shfl_xor(zz, 8);
        g[ms][rr] = 1.f / (1.f + __expf(-0.125f * zz));
      }
    }

    // G': p_{t+1} register loads (32 VGPRs, consumed next tile start).
    if (more) {
      const float4* prow =
          (const float4*)(pred + (((size_t)tbase + t + 1) * 32 + rA) * 256);
#pragma unroll
      for (int i = 0; i < 8; ++i) pv_[i] = prow[c8 + 8 * i];
    }

    // Pass 2: dV.
    f32x4 accV[2][4] = {};
    gemm_v(dcur, pv + woff, col, quad, accV);

    __syncthreads();  // all waves done reading dcur (d) and bufP

    // J: gdV -> dcur (XOR-chunk layout).
#pragma unroll
    for (int ms = 0; ms < 2; ++ms)
#pragma unroll
      for (int nt = 0; nt < 4; ++nt) {
        const int ch = w * 8 + nt * 2 + (col >> 3);
        const int j = col & 7;
#pragma unroll
        for (int rr = 0; rr < 4; ++rr) {
          const int row = ms * 16 + quad * 4 + rr;
          dcur[row * 256 + ((ch ^ (row & 7)) << 3) + j] =
              f2bf(g[ms][rr] * accV[ms][nt][rr]);
        }
      }
    // K/L: c1_t (and d_{t+1}) must have landed by pass3.
    asm volatile("s_waitcnt vmcnt(0)" ::: "memory");
    __syncthreads();

    // Pass 3: out = c1@Wvo^T + gdV@Wo^T + bvo.
    f32x4 accO1[2][4] = {};
    f32x4 accO2[2][4] = {};
    gemm_o(bufC1, dcur, pvo + woff, po + woff, col, quad, accO1, accO2);

    const size_t t0 = tg * 32;
#pragma unroll
    for (int ms = 0; ms < 2; ++ms)
#pragma unroll
      for (int nt = 0; nt < 4; ++nt)
#pragma unroll
        for (int rr = 0; rr < 4; ++rr)
          out[(t0 + ms * 16 + quad * 4 + rr) * 256 + nbase + nt * 16 + col] =
              accO1[ms][nt][rr] + accO2[ms][nt][rr] + bov[nt];

    __syncthreads();  // gate bufC1 / dcur reuse for next tile
  }
}

extern "C" void kernel_launch(void* const* d_in, const int* in_sizes, int n_in,
                              void* d_out, int out_size, void* d_ws, size_t ws_size,
                              hipStream_t stream) {
  const float* pred = (const float*)d_in[0];
  const float* cemb = (const float*)d_in[1];
  const float* Wq = (const float*)d_in[2];
  const float* bq = (const float*)d_in[3];
  const float* Wk = (const float*)d_in[4];
  const float* Wv = (const float*)d_in[6];
  const float* bv = (const float*)d_in[7];
  const float* Wo = (const float*)d_in[8];
  const float* bo = (const float*)d_in[9];
  float* out = (float*)d_out;

  short* pq = (short*)d_ws;
  short* pk = pq + 65536;
  short* pv = pk + 65536;
  short* po = pv + 65536;
  short* pvo = po + 65536;
  float* bvo = (float*)(pvo + 65536);  // total ws use: 656,384 bytes

  prep_kernel<<<288, 256, 0, stream>>>(Wq, Wk, Wv, Wo, bv, bo, pq, pk, pv, po, pvo, bvo);
  restage_kernel<<<2048, 256, 0, stream>>>(cemb, (short*)d_out);
  fused_kernel<<<512, 256, 0, stream>>>(pred, pq, pk, pv, po, pvo, bq, bvo, out);
}

// Round 6
// 319.805 us; speedup vs baseline: 2.1672x; 1.7586x over previous
//
#include <hip/hip_runtime.h>

typedef short short4v __attribute__((ext_vector_type(4)));
typedef short short8v __attribute__((ext_vector_type(8)));
typedef float f32x4 __attribute__((ext_vector_type(4)));

#define MFMA(a, b, c) __builtin_amdgcn_mfma_f32_16x16x32_bf16((a), (b), (c), 0, 0, 0)

__device__ __forceinline__ short f2bf(float f) {
  unsigned u = __float_as_uint(f);
  unsigned r = u + 0x7fffu + ((u >> 16) & 1u);  // round-to-nearest-even
  return (short)(r >> 16);
}

__device__ __forceinline__ short4v f2bf4(float4 v) {
  short4v s;
  s.x = f2bf(v.x); s.y = f2bf(v.y); s.z = f2bf(v.z); s.w = f2bf(v.w);
  return s;
}

// ---------------------------------------------------------------------------
// Image format (bf16): [64 rows][256 k]; 16B chunk c of row r stored at
// r*256 + ((c ^ (r&7))*8). A-fragment (row = ms*16 + col, chunk = ks*4+quad)
// reads then spread across 8 bank-quads per 16-lane group (b128-minimal).
// ---------------------------------------------------------------------------

// Packed B-weight: row n = h*64 + nt*16 + col, k = ks*32 + quad*8 + j
// -> packed[h*16384 + (ks*4+nt)*512 + (quad*16+col)*8 + j]; one fragment =
// one contiguous 1KB wave load.

// Merged prep: blocks 0..255 compute wvo = Wo@Wv (packed bf16) + bvo = Wo@bv+bo;
// blocks 256..287 pack Wq/Wk/Wv/Wo into fragment order.
__global__ __launch_bounds__(256) void prep_kernel(
    const float* __restrict__ Wq, const float* __restrict__ Wk,
    const float* __restrict__ Wv, const float* __restrict__ Wo,
    const float* __restrict__ bv, const float* __restrict__ bo,
    short* __restrict__ pq, short* __restrict__ pk,
    short* __restrict__ pv, short* __restrict__ po,
    short* __restrict__ pvo, float* __restrict__ bvo) {
  __shared__ float srow[256];
  __shared__ float red[256];
  if (blockIdx.x < 256) {
    const int n = blockIdx.x, k = threadIdx.x;
    const float wov = Wo[n * 256 + k];
    srow[k] = wov;
    red[k] = wov * bv[k];
    __syncthreads();
    float acc = 0.f;
#pragma unroll 16
    for (int j = 0; j < 256; ++j) acc += srow[j] * Wv[j * 256 + k];
    const int h = n >> 6, nt = (n >> 4) & 3, col = n & 15;
    const int ks = k >> 5, quad = (k >> 3) & 3, j8 = k & 7;
    pvo[h * 16384 + (ks * 4 + nt) * 512 + (quad * 16 + col) * 8 + j8] = f2bf(acc);
    for (int s = 128; s > 0; s >>= 1) {
      if (k < s) red[k] += red[k + s];
      __syncthreads();
    }
    if (k == 0) bvo[n] = red[0] + bo[n];
  } else {
    const int g = (blockIdx.x - 256) * 256 + threadIdx.x;  // 0..8191
    const int n = g >> 5;
    const int c8 = g & 31;
    const int h = n >> 6, nt = (n >> 4) & 3, col = n & 15;
    const int ks = c8 >> 2, quad = c8 & 3;
    const int src = n * 256 + c8 * 8;
    const int dst = h * 16384 + (ks * 4 + nt) * 512 + (quad * 16 + col) * 8;
    const float4* q4 = (const float4*)(Wq + src);
    const float4* k4 = (const float4*)(Wk + src);
    const float4* v4 = (const float4*)(Wv + src);
    const float4* o4 = (const float4*)(Wo + src);
    float4 qa = q4[0], qb = q4[1], ka = k4[0], kb = k4[1];
    float4 va = v4[0], vb = v4[1], oa = o4[0], ob = o4[1];
    *(short4v*)(pq + dst) = f2bf4(qa); *(short4v*)(pq + dst + 4) = f2bf4(qb);
    *(short4v*)(pk + dst) = f2bf4(ka); *(short4v*)(pk + dst + 4) = f2bf4(kb);
    *(short4v*)(pv + dst) = f2bf4(va); *(short4v*)(pv + dst + 4) = f2bf4(vb);
    *(short4v*)(po + dst) = f2bf4(oa); *(short4v*)(po + dst + 4) = f2bf4(ob);
  }
}

// M=64 block, 8 waves: wave w -> head h = w&3, N-half nhalf = w>>2 (32 cols).
// Each B fragment feeds 4 M-subtiles (acc[4][2]) -> L2 weight bytes per row
// halved vs the 32-row tile. X,Y are 32KB XOR-chunk images.
__global__ __launch_bounds__(512, 4) void fused_kernel(
    const float* __restrict__ pred, const float* __restrict__ cemb,
    const short* __restrict__ pq, const short* __restrict__ pk,
    const short* __restrict__ pv, const short* __restrict__ po,
    const short* __restrict__ pvo, const float* __restrict__ bq,
    const float* __restrict__ bvo, float* __restrict__ out) {
  __shared__ __align__(16) short X[16384];  // p image, later gdV image
  __shared__ __align__(16) short Y[16384];  // d image, later c1 image
  __shared__ float zbuf[512];               // [head][half][64 rows]
  const int tid = threadIdx.x;
  const int lane = tid & 63;
  const int w = tid >> 6;
  const int h = w & 3;
  const int nhalf = w >> 2;
  const int col = lane & 15;
  const int quad = lane >> 4;
  const int x7 = col & 7;
  const size_t t0 = (size_t)blockIdx.x * 64;
  const int rA = tid >> 3;  // staging row 0..63
  const int c8 = tid & 7;
  const int nbase = h * 64 + nhalf * 32;
  const short* wqp = pq + h * 16384 + nhalf * 1024 + lane * 8;
  const short* wkp = pk + h * 16384 + nhalf * 1024 + lane * 8;
  const short* wvp = pv + h * 16384 + nhalf * 1024 + lane * 8;
  const short* wop = po + h * 16384 + nhalf * 1024 + lane * 8;
  const short* wvop = pvo + h * 16384 + nhalf * 1024 + lane * 8;

  float bqv[2], bov[2];
#pragma unroll
  for (int n2 = 0; n2 < 2; ++n2) bqv[n2] = bq[nbase + n2 * 16 + col];
#pragma unroll
  for (int n2 = 0; n2 < 2; ++n2) bov[n2] = bvo[nbase + n2 * 16 + col];

  const float4* prow = (const float4*)(pred + (t0 + rA) * 256);
  const float4* crow = (const float4*)(cemb + (t0 + rA) * 512);
  const int rx = rA & 7;

  // ---- Stage: p -> X, d = c0-c1 -> Y (all transient registers) ----
  {
    float4 pvv[8], c0v[8], c1v[8];
#pragma unroll
    for (int i = 0; i < 8; ++i) pvv[i] = prow[c8 + 8 * i];
#pragma unroll
    for (int i = 0; i < 8; ++i) c0v[i] = crow[c8 + 8 * i];
#pragma unroll
    for (int i = 0; i < 8; ++i) c1v[i] = crow[64 + c8 + 8 * i];
#pragma unroll
    for (int i = 0; i < 8; ++i) {
      const int h2 = c8 + 8 * i;  // half-chunk 0..63
      const int off = rA * 256 + ((((h2 >> 1) ^ rx)) << 3) + (h2 & 1) * 4;
      *(short4v*)(X + off) = f2bf4(pvv[i]);
      float4 d4 = make_float4(c0v[i].x - c1v[i].x, c0v[i].y - c1v[i].y,
                              c0v[i].z - c1v[i].z, c0v[i].w - c1v[i].w);
      *(short4v*)(Y + off) = f2bf4(d4);
    }
  }
  __syncthreads();

  // ---- Pass 1: Q = p@Wq, dK = d@Wk (dual B-stream, acc[4][2] each) ----
  f32x4 accQ[4][2] = {};
  f32x4 accK[4][2] = {};
  {
    short8v qb0 = *(const short8v*)(wqp);
    short8v qb1 = *(const short8v*)(wqp + 512);
    short8v kb0 = *(const short8v*)(wkp);
    short8v kb1 = *(const short8v*)(wkp + 512);
#pragma unroll
    for (int ks = 0; ks < 8; ++ks) {
      const int kk = ((ks + 1) & 7) * 2048;
      short8v qn0 = *(const short8v*)(wqp + kk);
      short8v qn1 = *(const short8v*)(wqp + kk + 512);
      short8v kn0 = *(const short8v*)(wkp + kk);
      short8v kn1 = *(const short8v*)(wkp + kk + 512);
      const int ao = (((ks * 4 + quad) ^ x7) << 3);
#pragma unroll
      for (int ms = 0; ms < 4; ++ms) {
        const int ro = (ms * 16 + col) * 256 + ao;
        short8v ap = *(const short8v*)(X + ro);
        short8v ad = *(const short8v*)(Y + ro);
        accQ[ms][0] = MFMA(ap, qb0, accQ[ms][0]);
        accQ[ms][1] = MFMA(ap, qb1, accQ[ms][1]);
        accK[ms][0] = MFMA(ad, kb0, accK[ms][0]);
        accK[ms][1] = MFMA(ad, kb1, accK[ms][1]);
      }
      qb0 = qn0; qb1 = qn1; kb0 = kn0; kb1 = kn1;
    }
  }

  // ---- z half-sums -> zbuf; cross-half add; g = sigmoid(z/sqrt(D)) ----
  float g[4][4];
#pragma unroll
  for (int ms = 0; ms < 4; ++ms) {
#pragma unroll
    for (int rr = 0; rr < 4; ++rr) {
      float zz = (accQ[ms][0][rr] + bqv[0]) * accK[ms][0][rr] +
                 (accQ[ms][1][rr] + bqv[1]) * accK[ms][1][rr];
      zz += __shfl_xor(zz, 1);
      zz += __shfl_xor(zz, 2);
      zz += __shfl_xor(zz, 4);
      zz += __shfl_xor(zz, 8);
      g[ms][rr] = zz;  // stash half-sum
    }
  }
  if ((lane & 15) == 0) {
#pragma unroll
    for (int ms = 0; ms < 4; ++ms)
#pragma unroll
      for (int rr = 0; rr < 4; ++rr)
        zbuf[h * 128 + nhalf * 64 + ms * 16 + quad * 4 + rr] = g[ms][rr];
  }
  __syncthreads();
#pragma unroll
  for (int ms = 0; ms < 4; ++ms)
#pragma unroll
    for (int rr = 0; rr < 4; ++rr) {
      const int m = ms * 16 + quad * 4 + rr;
      const float zt = zbuf[h * 128 + m] + zbuf[h * 128 + 64 + m];
      g[ms][rr] = 1.f / (1.f + __expf(-0.125f * zt));
    }

  // Issue c1 re-load now (L2/L3-warm from staging); consumed after pass 2.
  float4 c1r[8];
#pragma unroll
  for (int i = 0; i < 8; ++i) c1r[i] = crow[64 + c8 + 8 * i];

  // ---- Pass 2: dV = d@Wv ----
  f32x4 accV[4][2] = {};
  {
    short8v vb0 = *(const short8v*)(wvp);
    short8v vb1 = *(const short8v*)(wvp + 512);
#pragma unroll
    for (int ks = 0; ks < 8; ++ks) {
      const int kk = ((ks + 1) & 7) * 2048;
      short8v vn0 = *(const short8v*)(wvp + kk);
      short8v vn1 = *(const short8v*)(wvp + kk + 512);
      const int ao = (((ks * 4 + quad) ^ x7) << 3);
#pragma unroll
      for (int ms = 0; ms < 4; ++ms) {
        short8v ad = *(const short8v*)(Y + (ms * 16 + col) * 256 + ao);
        accV[ms][0] = MFMA(ad, vb0, accV[ms][0]);
        accV[ms][1] = MFMA(ad, vb1, accV[ms][1]);
      }
      vb0 = vn0; vb1 = vn1;
    }
  }
  __syncthreads();  // all waves done reading X(p) and Y(d)

  // ---- gdV -> X; c1 -> Y ----
#pragma unroll
  for (int ms = 0; ms < 4; ++ms)
#pragma unroll
    for (int n2 = 0; n2 < 2; ++n2) {
      const int ch = h * 8 + nhalf * 4 + n2 * 2 + (col >> 3);
      const int j = col & 7;
#pragma unroll
      for (int rr = 0; rr < 4; ++rr) {
        const int row = ms * 16 + quad * 4 + rr;
        X[row * 256 + ((ch ^ (row & 7)) << 3) + j] =
            f2bf(g[ms][rr] * accV[ms][n2][rr]);
      }
    }
#pragma unroll
  for (int i = 0; i < 8; ++i) {
    const int h2 = c8 + 8 * i;
    const int off = rA * 256 + ((((h2 >> 1) ^ rx)) << 3) + (h2 & 1) * 4;
    *(short4v*)(Y + off) = f2bf4(c1r[i]);
  }
  __syncthreads();

  // ---- Pass 3: out = c1@Wvo^T + gdV@Wo^T + bvo (dual-A dual-B, one acc) ----
  f32x4 accO[4][2] = {};
  {
    short8v vb0 = *(const short8v*)(wvop);
    short8v vb1 = *(const short8v*)(wvop + 512);
    short8v ob0 = *(const short8v*)(wop);
    short8v ob1 = *(const short8v*)(wop + 512);
#pragma unroll
    for (int ks = 0; ks < 8; ++ks) {
      const int kk = ((ks + 1) & 7) * 2048;
      short8v vn0 = *(const short8v*)(wvop + kk);
      short8v vn1 = *(const short8v*)(wvop + kk + 512);
      short8v on0 = *(const short8v*)(wop + kk);
      short8v on1 = *(const short8v*)(wop + kk + 512);
      const int ao = (((ks * 4 + quad) ^ x7) << 3);
#pragma unroll
      for (int ms = 0; ms < 4; ++ms) {
        short8v ac = *(const short8v*)(Y + (ms * 16 + col) * 256 + ao);
        accO[ms][0] = MFMA(ac, vb0, accO[ms][0]);
        accO[ms][1] = MFMA(ac, vb1, accO[ms][1]);
      }
#pragma unroll
      for (int ms = 0; ms < 4; ++ms) {
        short8v ag = *(const short8v*)(X + (ms * 16 + col) * 256 + ao);
        accO[ms][0] = MFMA(ag, ob0, accO[ms][0]);
        accO[ms][1] = MFMA(ag, ob1, accO[ms][1]);
      }
      vb0 = vn0; vb1 = vn1; ob0 = on0; ob1 = on1;
    }
  }

#pragma unroll
  for (int ms = 0; ms < 4; ++ms)
#pragma unroll
    for (int n2 = 0; n2 < 2; ++n2)
#pragma unroll
      for (int rr = 0; rr < 4; ++rr)
        out[(t0 + ms * 16 + quad * 4 + rr) * 256 + nbase + n2 * 16 + col] =
            accO[ms][n2][rr] + bov[n2];
}

extern "C" void kernel_launch(void* const* d_in, const int* in_sizes, int n_in,
                              void* d_out, int out_size, void* d_ws, size_t ws_size,
                              hipStream_t stream) {
  const float* pred = (const float*)d_in[0];
  const float* cemb = (const float*)d_in[1];
  const float* Wq = (const float*)d_in[2];
  const float* bq = (const float*)d_in[3];
  const float* Wk = (const float*)d_in[4];
  const float* Wv = (const float*)d_in[6];
  const float* bv = (const float*)d_in[7];
  const float* Wo = (const float*)d_in[8];
  const float* bo = (const float*)d_in[9];
  float* out = (float*)d_out;

  short* pq = (short*)d_ws;
  short* pk = pq + 65536;
  short* pv = pk + 65536;
  short* po = pv + 65536;
  short* pvo = po + 65536;
  float* bvo = (float*)(pvo + 65536);  // total ws use: 656,384 bytes

  prep_kernel<<<288, 256, 0, stream>>>(Wq, Wk, Wv, Wo, bv, bo, pq, pk, pv, po, pvo, bvo);
  fused_kernel<<<1024, 512, 0, stream>>>(pred, cemb, pq, pk, pv, po, pvo, bq, bvo, out);
}